// Round 2
// baseline (111.048 us; speedup 1.0000x reference)
//
#include <hip/hip_runtime.h>

// GAT: B=4, N=2048, IN_DIM=128, H=4, D=64.
// R5 (resubmit after infra failure): factorized exp2 — exp2(leaky(s)) =
// max(E_i*F_j, G_i*H_j) with E,G,F,H precomputed in gat_linear epilogue (no
// v_exp_f32 in the attn hot loop; mask applied as integer AND with
// sign-extended adjacency bit). Attn loop widened to 128-j phases:
// Hl[2][64][128], one barrier per 2 tiles (33 -> 17 barriers), DMA restaged
// as 4 linear-in-lane global_load_lds per wave per phase.

#define NDIM 2048
#define LOG2E 1.4426950408889634f

typedef __bf16 bf16x8 __attribute__((ext_vector_type(8)));
typedef __bf16 bf16x4 __attribute__((ext_vector_type(4)));
typedef float  f32x4  __attribute__((ext_vector_type(4)));

#define LP 136   // linear LDS pitch (bf16)

__device__ static inline void load_lds16(const void* g, void* l) {
    __builtin_amdgcn_global_load_lds(
        (const __attribute__((address_space(1))) unsigned*)g,
        (__attribute__((address_space(3))) unsigned*)l, 16, 0, 0);
}

// ---------------- adj -> bitmask (bit k of word w = adj[w*32+k]) ----------------
__global__ __launch_bounds__(256) void adj_pack(const int* __restrict__ adj,
                                                unsigned* __restrict__ bits) {
    const int t = threadIdx.x;
    const int q = blockIdx.x * 256 + t;            // int4 index
    int4 a = ((const int4*)adj)[q];
    unsigned nib = (unsigned)(a.x > 0) | ((unsigned)(a.y > 0) << 1) |
                   ((unsigned)(a.z > 0) << 2) | ((unsigned)(a.w > 0) << 3);
    unsigned v = nib << ((t & 7) * 4);
    v |= __shfl_xor(v, 1, 64);
    v |= __shfl_xor(v, 2, 64);
    v |= __shfl_xor(v, 4, 64);
    if ((t & 7) == 0) bits[q >> 3] = v;
}

// ---------------- linear: h = x @ W^T (A=W rows -> C rows = out-channel) --------
// Epilogue stores float2 tables: es_ws[bh][n] = (exp2(es*log2e), exp2(0.2*es*log2e)),
// ed_ws[bh][n] = (exp2(ed*log2e), exp2(0.2*ed*log2e)).
__global__ __launch_bounds__(256) void gat_linear(
    const float* __restrict__ x, const float* __restrict__ W,
    const float* __restrict__ att_src, const float* __restrict__ att_dst,
    __bf16* __restrict__ h_t, float* __restrict__ es_ws, float* __restrict__ ed_ws)
{
    const int t    = threadIdx.x;
    const int head = blockIdx.x & 3;
    const int n0g  = (blockIdx.x >> 2) * 64;       // global row in [0, 8192)
    const int b    = n0g >> 11;
    const int n0   = n0g & (NDIM - 1);
    const int bh   = b * 4 + head;

    __shared__ __align__(16) __bf16 Wl[64][LP];    // 17.4 KB
    __shared__ __align__(16) __bf16 Xl[64][LP];    // 17.4 KB

    #pragma unroll
    for (int i = 0; i < 8; ++i) {
        int idx = t + i * 256;
        int r = idx >> 5, c4 = idx & 31;
        float4 wv = *((const float4*)(W + (size_t)(head * 64 + r) * 128) + c4);
        bf16x4 bv;
        bv[0] = (__bf16)wv.x; bv[1] = (__bf16)wv.y; bv[2] = (__bf16)wv.z; bv[3] = (__bf16)wv.w;
        *(bf16x4*)&Wl[r][c4 * 4] = bv;
    }
    #pragma unroll
    for (int i = 0; i < 8; ++i) {
        int idx = t + i * 256;
        int r = idx >> 5, c4 = idx & 31;
        float4 xv = *((const float4*)(x + (size_t)(n0g + r) * 128) + c4);
        bf16x4 bv;
        bv[0] = (__bf16)xv.x; bv[1] = (__bf16)xv.y; bv[2] = (__bf16)xv.z; bv[3] = (__bf16)xv.w;
        *(bf16x4*)&Xl[r][c4 * 4] = bv;
    }
    __syncthreads();

    const int lane = t & 63, w = t >> 6;
    const int m = lane & 15, q4 = lane >> 4;

    bf16x8 bfr[4];
    #pragma unroll
    for (int ks = 0; ks < 4; ++ks)
        bfr[ks] = *(const bf16x8*)&Xl[w * 16 + m][ks * 32 + q4 * 8];

    f32x4 acc[4];
    #pragma unroll
    for (int c = 0; c < 4; ++c) acc[c] = (f32x4){0.f, 0.f, 0.f, 0.f};

    #pragma unroll
    for (int ct = 0; ct < 4; ++ct) {
        #pragma unroll
        for (int ks = 0; ks < 4; ++ks) {
            bf16x8 afr = *(const bf16x8*)&Wl[ct * 16 + m][ks * 32 + q4 * 8];
            acc[ct] = __builtin_amdgcn_mfma_f32_16x16x32_bf16(afr, bfr[ks], acc[ct], 0, 0, 0);
        }
    }

    // epilogue: h_t[bh][d][n] (n-contiguous) + es/ed reductions over d
    const int nloc = n0 + w * 16 + m;
    float esA = 0.f, edA = 0.f;
    #pragma unroll
    for (int ct = 0; ct < 4; ++ct) {
        float4 aS = *(const float4*)(att_src + head * 64 + ct * 16 + q4 * 4);
        float4 aD = *(const float4*)(att_dst + head * 64 + ct * 16 + q4 * 4);
        #pragma unroll
        for (int r = 0; r < 4; ++r) {
            float v = acc[ct][r];
            int   d = ct * 16 + q4 * 4 + r;
            h_t[(size_t)(bh * 64 + d) * NDIM + nloc] = (__bf16)v;
            esA += v * ((const float*)&aS)[r];
            edA += v * ((const float*)&aD)[r];
        }
    }
    esA += __shfl_xor(esA, 16, 64); esA += __shfl_xor(esA, 32, 64);
    edA += __shfl_xor(edA, 16, 64); edA += __shfl_xor(edA, 32, 64);
    if (lane < 16) {
        float s2 = esA * LOG2E, d2 = edA * LOG2E;
        float2 ev, dv;
        ev.x = __builtin_amdgcn_exp2f(s2);
        ev.y = __builtin_amdgcn_exp2f(0.2f * s2);
        dv.x = __builtin_amdgcn_exp2f(d2);
        dv.y = __builtin_amdgcn_exp2f(0.2f * d2);
        ((float2*)es_ws)[(size_t)bh * NDIM + nloc] = ev;
        ((float2*)ed_ws)[(size_t)bh * NDIM + nloc] = dv;
    }
}

// ---------------- attention: 128-wide phases, factorized-exp p-gen, MFMA PV ----
// grid 512: bh = blk & 15, it = blk >> 4. Wave w stages d-rows w*16..w*16+15.
// Hl[buf][d][128]: within each 64-col half, chunk c8 of row d holds j-chunk
// (c8 ^ (d&7)). DMA: 4 instrs/wave/phase, each 4 rows x 128 cols, linear in lane.
__global__ __launch_bounds__(256) void gat_attn(
    const unsigned long long* __restrict__ bits, const __bf16* __restrict__ h_t,
    const float* __restrict__ es_ws, const float* __restrict__ ed_ws,
    float* __restrict__ out)
{
    const int blk = blockIdx.x;
    const int bh  = blk & 15;
    const int i0  = (blk >> 4) * 64;
    const int t   = threadIdx.x;
    const int lane = t & 63, w = t >> 6;
    const int m = lane & 15, q4 = lane >> 4;

    __shared__ __align__(16) __bf16 Hl[2][64][128];   // 32 KB

    // DMA lane map: instr k stages d-rows w*16+k*4 .. +3, full 128 cols.
    // lane -> row w*16+k*4+(lane>>4), chunk lane&15 (half = bit3, c8 = low 3).
    const int lh   = lane >> 4;          // 0..3 row-sub
    const int c8   = lane & 7;           // 8-bf16 chunk within half
    const int half = (lane >> 3) & 1;    // j-tile parity within the 128-col phase
    const __bf16* gA  = h_t + (size_t)(bh * 64 + w * 16 + lh) * NDIM
                        + half * 64 + (c8 ^ lh) * 8;
    const __bf16* gB  = h_t + (size_t)(bh * 64 + w * 16 + 4 + lh) * NDIM
                        + half * 64 + ((c8 ^ lh ^ 4)) * 8;
    const __bf16* gA2 = gA + 8 * NDIM;
    const __bf16* gB2 = gB + 8 * NDIM;
    __bf16* const ld0 = &Hl[0][0][0] + w * 2048 + lane * 8;  // buf0 base, lane-linear

    const float2 eg = ((const float2*)es_ws)[(size_t)bh * NDIM + i0 + w * 16 + m];
    const float egx = eg.x, egy = eg.y;                       // E_i, G_i
    const unsigned long long* brow = bits + (size_t)(i0 + w * 16 + m) * 32;
    const float* edp = ed_ws + ((size_t)bh * NDIM + q4 * 8) * 2;   // (F,H) pairs

    // prologue: tiles 0,1 -> buf0
    load_lds16(gA,  ld0);
    load_lds16(gB,  ld0 + 512);
    load_lds16(gA2, ld0 + 1024);
    load_lds16(gB2, ld0 + 1536);

    float fh[2][32];                    // (F,H) interleaved, 16 j per tile-slot
    unsigned long long bwb[2];
    #pragma unroll
    for (int g = 0; g < 8; ++g)
        *(float4*)&fh[0][g * 4] = *(const float4*)(edp + (g >> 2) * 64 + (g & 3) * 4);
    bwb[0] = brow[0];

    f32x4 acc[4], accl;
    #pragma unroll
    for (int c = 0; c < 4; ++c) acc[c] = (f32x4){0.f, 0.f, 0.f, 0.f};
    accl = (f32x4){0.f, 0.f, 0.f, 0.f};
    bf16x8 ones;
    #pragma unroll
    for (int jj = 0; jj < 8; ++jj) ones[jj] = (__bf16)1.0f;
    const int sw = m & 7;

    __syncthreads();    // drains tile-0/1 DMA

#define STEP(ITJ, FP, HB)                                                        \
    {                                                                            \
        const int itj = (ITJ);                                                   \
        if (itj < 31) {                                                          \
            const float* ep = edp + (size_t)(itj + 1) * 128;                     \
            _Pragma("unroll")                                                    \
            for (int g = 0; g < 8; ++g)                                          \
                *(float4*)&fh[(FP) ^ 1][g * 4] =                                 \
                    *(const float4*)(ep + (g >> 2) * 64 + (g & 3) * 4);          \
            bwb[(FP) ^ 1] = brow[itj + 1];                                       \
        }                                                                        \
        bf16x8 af[2];                                                            \
        _Pragma("unroll")                                                        \
        for (int ks = 0; ks < 2; ++ks) {                                         \
            unsigned bm = (unsigned)(bwb[FP] >> (ks * 32 + q4 * 8)) & 0xFFu;     \
            _Pragma("unroll")                                                    \
            for (int jj = 0; jj < 8; ++jj) {                                     \
                float t1 = egx * fh[FP][ks * 16 + jj * 2];                       \
                float t2 = egy * fh[FP][ks * 16 + jj * 2 + 1];                   \
                float p = fmaxf(t1, t2);                                         \
                int mk = ((int)(bm << (31 - jj))) >> 31;                         \
                p = __int_as_float(__float_as_int(p) & mk);                      \
                af[ks][jj] = (__bf16)p;                                          \
            }                                                                    \
        }                                                                        \
        _Pragma("unroll")                                                        \
        for (int ks = 0; ks < 2; ++ks) {                                         \
            accl = __builtin_amdgcn_mfma_f32_16x16x32_bf16(af[ks], ones, accl, 0, 0, 0); \
            _Pragma("unroll")                                                    \
            for (int ct = 0; ct < 4; ++ct) {                                     \
                bf16x8 bfr = *(const bf16x8*)&Hl[HB][ct * 16 + m][(FP) * 64 + ((ks * 4 + q4) ^ sw) * 8]; \
                acc[ct] = __builtin_amdgcn_mfma_f32_16x16x32_bf16(af[ks], bfr, acc[ct], 0, 0, 0); \
            }                                                                    \
        }                                                                        \
    }

    for (int ph = 0; ph < 16; ++ph) {
        const int Pb = ph & 1;
        if (ph < 15) {                       // prefetch tiles 2ph+2, 2ph+3 -> buf Pb^1
            const size_t tb = (size_t)(ph + 1) * 128;
            __bf16* dst = ld0 + (Pb ^ 1) * 8192;
            load_lds16(gA  + tb, dst);
            load_lds16(gB  + tb, dst + 512);
            load_lds16(gA2 + tb, dst + 1024);
            load_lds16(gB2 + tb, dst + 1536);
        }
        STEP(2 * ph,     0, Pb)
        STEP(2 * ph + 1, 1, Pb)
        __syncthreads();                     // one barrier per 2 tiles
    }
#undef STEP

    // accl[r] = l for output row q4*4+r (all m-lanes identical) — no shuffles
    float invr[4];
    #pragma unroll
    for (int r = 0; r < 4; ++r) invr[r] = 1.f / accl[r];

    const int b = bh >> 2, head = bh & 3;
    float* ob = out + ((size_t)(b * NDIM + i0 + w * 16)) * 256 + head * 64;
    #pragma unroll
    for (int ct = 0; ct < 4; ++ct) {
        #pragma unroll
        for (int r = 0; r < 4; ++r) {
            ob[(size_t)(q4 * 4 + r) * 256 + ct * 16 + m] = acc[ct][r] * invr[r];
        }
    }
}

extern "C" void kernel_launch(void* const* d_in, const int* in_sizes, int n_in,
                              void* d_out, int out_size, void* d_ws, size_t ws_size,
                              hipStream_t stream) {
    const float* x       = (const float*)d_in[0];
    const int*   adj     = (const int*)d_in[1];
    const float* W       = (const float*)d_in[2];
    const float* att_src = (const float*)d_in[3];
    const float* att_dst = (const float*)d_in[4];
    float* out = (float*)d_out;

    __bf16*   h_t   = (__bf16*)d_ws;                              // 4 MB
    float*    es_ws = (float*)((char*)d_ws + (size_t)4 * 1024 * 1024);  // 256 KB (float2)
    float*    ed_ws = es_ws + (size_t)16 * NDIM * 2;              // 256 KB (float2)
    unsigned* bitsp = (unsigned*)(ed_ws + (size_t)16 * NDIM * 2); // 512 KB

    adj_pack<<<NDIM * NDIM / 4 / 256, 256, 0, stream>>>(adj, bitsp);
    gat_linear<<<512, 256, 0, stream>>>(x, W, att_src, att_dst, h_t, es_ws, ed_ws);
    gat_attn<<<512, 256, 0, stream>>>((const unsigned long long*)bitsp, h_t, es_ws, ed_ws, out);
}

// Round 3
// 105.692 us; speedup vs baseline: 1.0507x; 1.0507x over previous
//
#include <hip/hip_runtime.h>

// GAT: B=4, N=2048, IN_DIM=128, H=4, D=64.
// R6: occupancy attack. gat_attn -> 512-thread blocks, 8 waves: waves 0-3 do
// j in [0,1024), waves 4-7 do j in [1024,2048) (16 tiles each instead of 32),
// LDS combine of (acc, l) partials at the end. 2 blocks/CU => 4 waves/SIMD
// (was 2) and half the per-wave serial barrier/DMA chain. Score path = R4
// (exp2 in loop) to keep VGPR <= 128. adj_pack fused into gat_pre fat kernel.

#define NDIM 2048
#define NEG_SLOPE 0.2f
#define LOG2E 1.4426950408889634f

typedef __bf16 bf16x8 __attribute__((ext_vector_type(8)));
typedef __bf16 bf16x4 __attribute__((ext_vector_type(4)));
typedef float  f32x4  __attribute__((ext_vector_type(4)));

#define LP 136   // linear LDS pitch (bf16)

__device__ static inline void load_lds16(const void* g, void* l) {
    __builtin_amdgcn_global_load_lds(
        (const __attribute__((address_space(1))) unsigned*)g,
        (__attribute__((address_space(3))) unsigned*)l, 16, 0, 0);
}

// ---------------- fused: adj bit-pack (blocks >= 512) + linear (blocks < 512) --
// adj: bit k of word w = adj[w*32+k].
// linear: h = x @ W^T; epilogue emits h_t[bh][d][n] + es/ed (pre-scaled LOG2E).
__global__ __launch_bounds__(256) void gat_pre(
    const float* __restrict__ x, const int* __restrict__ adj,
    const float* __restrict__ W, const float* __restrict__ att_src,
    const float* __restrict__ att_dst, __bf16* __restrict__ h_t,
    float* __restrict__ es_ws, float* __restrict__ ed_ws,
    unsigned* __restrict__ bits)
{
    const int t = threadIdx.x;

    if (blockIdx.x >= 512) {
        // ---- adj_pack ----
        const int q = (blockIdx.x - 512) * 256 + t;    // int4 index
        int4 a = ((const int4*)adj)[q];
        unsigned nib = (unsigned)(a.x > 0) | ((unsigned)(a.y > 0) << 1) |
                       ((unsigned)(a.z > 0) << 2) | ((unsigned)(a.w > 0) << 3);
        unsigned v = nib << ((t & 7) * 4);
        v |= __shfl_xor(v, 1, 64);
        v |= __shfl_xor(v, 2, 64);
        v |= __shfl_xor(v, 4, 64);
        if ((t & 7) == 0) bits[q >> 3] = v;
        return;
    }

    // ---- linear ----
    const int head = blockIdx.x & 3;
    const int n0g  = (blockIdx.x >> 2) * 64;       // global row in [0, 8192)
    const int b    = n0g >> 11;
    const int n0   = n0g & (NDIM - 1);
    const int bh   = b * 4 + head;

    __shared__ __align__(16) __bf16 Wl[64][LP];    // 17.4 KB
    __shared__ __align__(16) __bf16 Xl[64][LP];    // 17.4 KB

    #pragma unroll
    for (int i = 0; i < 8; ++i) {
        int idx = t + i * 256;
        int r = idx >> 5, c4 = idx & 31;
        float4 wv = *((const float4*)(W + (size_t)(head * 64 + r) * 128) + c4);
        bf16x4 bv;
        bv[0] = (__bf16)wv.x; bv[1] = (__bf16)wv.y; bv[2] = (__bf16)wv.z; bv[3] = (__bf16)wv.w;
        *(bf16x4*)&Wl[r][c4 * 4] = bv;
    }
    #pragma unroll
    for (int i = 0; i < 8; ++i) {
        int idx = t + i * 256;
        int r = idx >> 5, c4 = idx & 31;
        float4 xv = *((const float4*)(x + (size_t)(n0g + r) * 128) + c4);
        bf16x4 bv;
        bv[0] = (__bf16)xv.x; bv[1] = (__bf16)xv.y; bv[2] = (__bf16)xv.z; bv[3] = (__bf16)xv.w;
        *(bf16x4*)&Xl[r][c4 * 4] = bv;
    }
    __syncthreads();

    const int lane = t & 63, w = t >> 6;
    const int m = lane & 15, q4 = lane >> 4;

    bf16x8 bfr[4];
    #pragma unroll
    for (int ks = 0; ks < 4; ++ks)
        bfr[ks] = *(const bf16x8*)&Xl[w * 16 + m][ks * 32 + q4 * 8];

    f32x4 acc[4];
    #pragma unroll
    for (int c = 0; c < 4; ++c) acc[c] = (f32x4){0.f, 0.f, 0.f, 0.f};

    #pragma unroll
    for (int ct = 0; ct < 4; ++ct) {
        #pragma unroll
        for (int ks = 0; ks < 4; ++ks) {
            bf16x8 afr = *(const bf16x8*)&Wl[ct * 16 + m][ks * 32 + q4 * 8];
            acc[ct] = __builtin_amdgcn_mfma_f32_16x16x32_bf16(afr, bfr[ks], acc[ct], 0, 0, 0);
        }
    }

    const int nloc = n0 + w * 16 + m;
    float esA = 0.f, edA = 0.f;
    #pragma unroll
    for (int ct = 0; ct < 4; ++ct) {
        float4 aS = *(const float4*)(att_src + head * 64 + ct * 16 + q4 * 4);
        float4 aD = *(const float4*)(att_dst + head * 64 + ct * 16 + q4 * 4);
        #pragma unroll
        for (int r = 0; r < 4; ++r) {
            float v = acc[ct][r];
            int   d = ct * 16 + q4 * 4 + r;
            h_t[(size_t)(bh * 64 + d) * NDIM + nloc] = (__bf16)v;
            esA += v * ((const float*)&aS)[r];
            edA += v * ((const float*)&aD)[r];
        }
    }
    esA += __shfl_xor(esA, 16, 64); esA += __shfl_xor(esA, 32, 64);
    edA += __shfl_xor(edA, 16, 64); edA += __shfl_xor(edA, 32, 64);
    if (lane < 16) {
        es_ws[bh * NDIM + nloc] = esA * LOG2E;   // pre-scaled: exp2 domain
        ed_ws[bh * NDIM + nloc] = edA * LOG2E;
    }
}

// ---------------- attention: 8-wave j-split + DMA-staged Hl + MFMA PV ---------
// grid 512: bh = blk & 15, i-tile = blk >> 4. Wave w: group gJ = w>>2 owns
// j-range gJ*1024 + [0,1024) (16 tiles of 64), local wave wl = w&3 owns A-rows
// i0 + wl*16 + m. Hl[gJ][buf][d][64] XOR-swizzled as in R4. End: group 1
// stores (acc,l) to LDS scratch; group 0 adds, normalizes, writes out.
__global__ __launch_bounds__(512, 4) void gat_attn(
    const unsigned long long* __restrict__ bits, const __bf16* __restrict__ h_t,
    const float* __restrict__ es_ws, const float* __restrict__ ed_ws,
    float* __restrict__ out)
{
    const int blk = blockIdx.x;
    const int bh  = blk & 15;
    const int i0  = (blk >> 4) * 64;
    const int t   = threadIdx.x;
    const int lane = t & 63, w = t >> 6;
    const int gJ = w >> 2, wl = w & 3;
    const int m = lane & 15, q4 = lane >> 4;

    __shared__ __align__(16) __bf16 Hl[2][2][64][64];   // [group][buf][d][j] 32 KB

    // DMA lanes: wave (gJ,wl) stages d-rows wl*16..wl*16+15 of group gJ's buffers
    const int r0 = wl * 16 + (lane >> 3);
    const int r1 = r0 + 8;
    const int c8 = lane & 7;
    const size_t jbase = (size_t)gJ * 1024;
    const __bf16* g0 = h_t + ((size_t)(bh * 64 + r0)) * NDIM + jbase + ((c8 ^ (r0 & 7)) * 8);
    const __bf16* g1 = h_t + ((size_t)(bh * 64 + r1)) * NDIM + jbase + ((c8 ^ (r1 & 7)) * 8);
    __bf16* l0a = &Hl[gJ][0][r0][c8 * 8];
    __bf16* l0b = &Hl[gJ][0][r1][c8 * 8];
    __bf16* l1a = &Hl[gJ][1][r0][c8 * 8];
    __bf16* l1b = &Hl[gJ][1][r1][c8 * 8];

    const float es2 = es_ws[bh * NDIM + i0 + wl * 16 + m];          // *log2e already
    const unsigned long long* brow = bits + (size_t)(i0 + wl * 16 + m) * 32 + gJ * 16;
    const float* edp = ed_ws + bh * NDIM + jbase + q4 * 8;          // *log2e already

    // preload tile 0 of this group's j-range: DMA + scalar prefetch
    load_lds16(g0, l0a);
    load_lds16(g1, l0b);
    float eb[2][16];
    unsigned long long bwb[2];
    #pragma unroll
    for (int g4 = 0; g4 < 4; ++g4)
        *(float4*)&eb[0][g4 * 4] = *(const float4*)(edp + (g4 >> 1) * 32 + (g4 & 1) * 4);
    bwb[0] = brow[0];

    f32x4 acc[4], accl;
    #pragma unroll
    for (int c = 0; c < 4; ++c) acc[c] = (f32x4){0.f, 0.f, 0.f, 0.f};
    accl = (f32x4){0.f, 0.f, 0.f, 0.f};
    bf16x8 ones;
    #pragma unroll
    for (int jj = 0; jj < 8; ++jj) ones[jj] = (__bf16)1.0f;
    const int sw = m & 7;

    __syncthreads();    // drains tile-0 DMA (all groups)

#define STEP(ITJ, P)                                                            \
    {                                                                           \
        const int itj = (ITJ);                                                  \
        if (itj < 15) {                                                         \
            load_lds16(g0 + (itj + 1) * 64, (P) ? l0a : l1a);                   \
            load_lds16(g1 + (itj + 1) * 64, (P) ? l0b : l1b);                   \
            const float* ep = edp + (itj + 1) * 64;                             \
            _Pragma("unroll")                                                   \
            for (int g4 = 0; g4 < 4; ++g4)                                      \
                *(float4*)&eb[(P) ^ 1][g4 * 4] =                                \
                    *(const float4*)(ep + (g4 >> 1) * 32 + (g4 & 1) * 4);       \
            bwb[(P) ^ 1] = brow[itj + 1];                                       \
        }                                                                       \
        bf16x8 af[2];                                                           \
        _Pragma("unroll")                                                       \
        for (int ks = 0; ks < 2; ++ks) {                                        \
            unsigned bm = (unsigned)(bwb[P] >> (ks * 32 + q4 * 8)) & 0xFFu;     \
            _Pragma("unroll")                                                   \
            for (int jj = 0; jj < 8; ++jj) {                                    \
                float s = es2 + eb[P][ks * 8 + jj];                             \
                s = fmaxf(s, NEG_SLOPE * s);                                    \
                s = ((bm >> jj) & 1u) ? s : -10000.0f;                          \
                af[ks][jj] = (__bf16)__builtin_amdgcn_exp2f(s);                 \
            }                                                                   \
        }                                                                       \
        _Pragma("unroll")                                                       \
        for (int ks = 0; ks < 2; ++ks) {                                        \
            accl = __builtin_amdgcn_mfma_f32_16x16x32_bf16(af[ks], ones, accl, 0, 0, 0); \
            _Pragma("unroll")                                                   \
            for (int ct = 0; ct < 4; ++ct) {                                    \
                bf16x8 bfr = *(const bf16x8*)&Hl[gJ][P][ct * 16 + m][((ks * 4 + q4) ^ sw) * 8]; \
                acc[ct] = __builtin_amdgcn_mfma_f32_16x16x32_bf16(af[ks], bfr, acc[ct], 0, 0, 0); \
            }                                                                   \
        }                                                                       \
        __syncthreads();                                                        \
    }

    for (int it2 = 0; it2 < 8; ++it2) {
        STEP(it2 * 2, 0);
        STEP(it2 * 2 + 1, 1);
    }
#undef STEP

    // ---- combine group partials via LDS scratch (reuses Hl; all reads done) ----
    float* sc = (float*)&Hl[0][0][0][0];           // 256 lanes * 24 f32 = 24 KB
    const int sidx = (wl * 64 + lane) * 24;        // 96 B stride: aligned, few conflicts
    if (w >= 4) {
        #pragma unroll
        for (int ct = 0; ct < 4; ++ct) *(f32x4*)&sc[sidx + ct * 4] = acc[ct];
        *(f32x4*)&sc[sidx + 16] = accl;
    }
    __syncthreads();
    if (w < 4) {
        #pragma unroll
        for (int ct = 0; ct < 4; ++ct) {
            f32x4 o = *(const f32x4*)&sc[sidx + ct * 4];
            acc[ct] = acc[ct] + o;
        }
        f32x4 lo = *(const f32x4*)&sc[sidx + 16];
        accl = accl + lo;

        float invr[4];
        #pragma unroll
        for (int r = 0; r < 4; ++r) invr[r] = 1.f / accl[r];

        const int b = bh >> 2, head = bh & 3;
        float* ob = out + ((size_t)(b * NDIM + i0 + wl * 16)) * 256 + head * 64;
        #pragma unroll
        for (int ct = 0; ct < 4; ++ct) {
            #pragma unroll
            for (int r = 0; r < 4; ++r) {
                ob[(size_t)(q4 * 4 + r) * 256 + ct * 16 + m] = acc[ct][r] * invr[r];
            }
        }
    }
}

extern "C" void kernel_launch(void* const* d_in, const int* in_sizes, int n_in,
                              void* d_out, int out_size, void* d_ws, size_t ws_size,
                              hipStream_t stream) {
    const float* x       = (const float*)d_in[0];
    const int*   adj     = (const int*)d_in[1];
    const float* W       = (const float*)d_in[2];
    const float* att_src = (const float*)d_in[3];
    const float* att_dst = (const float*)d_in[4];
    float* out = (float*)d_out;

    __bf16*   h_t   = (__bf16*)d_ws;                              // 4 MB
    float*    es_ws = (float*)((char*)d_ws + (size_t)4 * 1024 * 1024);
    float*    ed_ws = es_ws + 16 * NDIM;                          // 128 KB each
    unsigned* bitsp = (unsigned*)(ed_ws + 16 * NDIM);             // 512 KB

    // blocks [0,512) = linear, [512,4608) = adj bit-pack
    gat_pre<<<4608, 256, 0, stream>>>(x, adj, W, att_src, att_dst, h_t, es_ws, ed_ws, bitsp);
    gat_attn<<<512, 512, 0, stream>>>((const unsigned long long*)bitsp, h_t, es_ws, ed_ws, out);
}